// Round 19
// baseline (208.837 us; speedup 1.0000x reference)
//
#include <hip/hip_runtime.h>
#include <hip/hip_bf16.h>

// Problem constants (B,DIM,H,W)=(4,256,64,64), DSTATE=64, EXPAND=2, DCONV=4
// DINNER=512, HEADDIM=64, NHEADS=8, DINPROJ=1160, CONVDIM=640, EPS=1e-5
#define EPSF 1e-5f

typedef unsigned short u16;
typedef __attribute__((ext_vector_type(8))) short short8;   // 8 x bf16 MFMA operand
typedef __attribute__((ext_vector_type(4))) float f32x4;    // MFMA accumulator

__device__ __forceinline__ float sigf(float x){ return 1.f/(1.f+__expf(-x)); }
__device__ __forceinline__ float siluf(float x){ return x/(1.f+__expf(-x)); }
__device__ __forceinline__ u16 f2bf(float x){ __hip_bfloat16 h = __float2bfloat16(x); return *reinterpret_cast<u16*>(&h); }
__device__ __forceinline__ float bf2f(u16 u){ __hip_bfloat16 h; *reinterpret_cast<u16*>(&h) = u; return __bfloat162float(h); }

union BF8 { short8 v; u16 h[8]; uint4 q; };

__device__ __forceinline__ short8 ldg_frag(const u16* p){
  BF8 u; u.q = *(const uint4*)p; return u.v;
}
#define MFMA16(a,b,c) __builtin_amdgcn_mfma_f32_16x16x32_bf16((a),(b),(c),0,0,0)

// ---------------- K0: channel LayerNorm, x (B,C,H,W) -> xn bf16 (B,H,W,C) ----------------
__global__ __launch_bounds__(256) void k_ln(const float* __restrict__ x,
                                            const float* __restrict__ g,
                                            const float* __restrict__ b,
                                            u16* __restrict__ xn){
  __shared__ float XL[256][65];
  __shared__ float red[2][4][64];
  __shared__ float muL[64], rsL[64];
  int blk = blockIdx.x; int bb = blk>>6, h = blk&63;
  int t = threadIdx.x;
  const float* xb = x + ((size_t)bb*256*4096) + h*64;
  for(int i=0;i<64;i++){ int idx = t + 256*i; int c = idx>>6, w = idx&63;
    XL[c][w] = xb[(size_t)c*4096 + w]; }
  __syncthreads();
  { int w = t & 63, q = t >> 6;
    float s1=0, s2=0;
    for(int c=q*64;c<q*64+64;c++){ float v = XL[c][w]; s1+=v; s2+=v*v; }
    red[0][q][w]=s1; red[1][q][w]=s2; }
  __syncthreads();
  if(t<64){ float a=0,c2=0;
    for(int q=0;q<4;q++){a+=red[0][q][t]; c2+=red[1][q][t];}
    float mu=a*(1.f/256.f); float var=c2*(1.f/256.f)-mu*mu;
    muL[t]=mu; rsL[t]=rsqrtf(var+EPSF); }
  __syncthreads();
  u16* xnb = xn + (size_t)(bb*64+h)*64*256;
  for(int i=0;i<64;i++){ int idx = t + 256*i; int w = idx>>8, c = idx&255;
    float v = (XL[c][w]-muL[w])*rsL[w]*g[c]+b[c];
    xnb[w*256 + c] = f2bf(v); }
}

// ---------------- K_prep: pack Wi frags (blocks 0..145) + Wcomb=Wo@W1^T (blocks 146..657) ----
__global__ __launch_bounds__(256) void k_prep(const float* __restrict__ Wi,
                                              u16* __restrict__ WiF,
                                              const float* __restrict__ Wo,
                                              const float* __restrict__ W1,
                                              u16* __restrict__ WCF){
  __shared__ float WoL[256];
  int blk = blockIdx.x;
  int t = threadIdx.x;
  if(blk < 146){
    int f = blk*256 + t;                  // 37376 threads exactly
    int lane = f & 63, kk = (f>>6)&7, ji = f>>9;
    int g = lane>>4, c16 = lane&15;
    int j = ji*16 + c16;
    BF8 o;
    #pragma unroll
    for(int i=0;i<8;i++){
      int k = kk*32 + g*8 + i;
      o.h[i] = (j < 1160) ? f2bf(Wi[(size_t)k*1160 + j]) : (u16)0;
    }
    *(uint4*)(WiF + (size_t)f*8) = o.q;
  } else {
    int k = blk - 146;                    // 0..511
    int o = t;                            // 0..255
    WoL[o] = Wo[(size_t)k*256 + o];
    __syncthreads();
    const float4* w1p = (const float4*)(W1 + (size_t)o*256);
    const float4* wop = (const float4*)WoL;
    float d = 0.f;
    #pragma unroll 8
    for(int i=0;i<64;i++){
      float4 a = wop[i]; float4 b = w1p[i];
      d += a.x*b.x + a.y*b.y + a.z*b.z + a.w*b.w;
    }
    int kk = k>>5, g = (k>>3)&3, i2 = k&7;
    int ci = o>>4, c16 = o&15;
    WCF[(size_t)((((ci*16+kk)*4+g)*16+c16)*8 + i2)] = f2bf(d);
  }
}

// ---------------- K1: in-projection GEMM (once; direction-independent) ----------------
// grid 1280 1D, XCD-swizzled so the 5 col-chunk blocks of each row-block share one XCD L2.
__global__ __launch_bounds__(512, 4) void k_gemm_in(const u16* __restrict__ xn,
    const u16* __restrict__ WiF, const float* __restrict__ dtb,
    const float* __restrict__ alog,
    u16* __restrict__ zg, u16* __restrict__ xbc,
    float* __restrict__ dtp, float* __restrict__ dtA){
  __shared__ u16 XL[64][264];     // A tile 64x256 bf16, pad 264 (33.8 KB)
  int id = blockIdx.x;
  int xcd = id & 7;
  int rem = id >> 3;              // 0..159
  int rb_local = rem / 5;
  int cb = rem - rb_local*5;
  int rb = xcd*32 + rb_local;
  int t = threadIdx.x;
  int w = t>>6, lane = t&63, g = lane>>4, c16 = lane&15;

  const u16* asrc = xn + (size_t)rb*64*256;
  #pragma unroll
  for(int i=0;i<4;i++){
    int idx = t + 512*i;
    int row = idx>>5, ch = idx&31;
    *(uint4*)&XL[row][ch*8] = *(const uint4*)(asrc + (size_t)row*256 + ch*8);
  }
  __syncthreads();

  int jbase = cb*15;
  int jcount = (cb==4) ? 13 : 15;
  int jl0 = w*2;

  f32x4 acc[2][4];
  #pragma unroll
  for(int jj=0;jj<2;jj++){
    #pragma unroll
    for(int li=0;li<4;li++) acc[jj][li] = (f32x4){0.f,0.f,0.f,0.f};
  }
  #pragma unroll
  for(int kk=0;kk<8;++kk){
    short8 a0 = *(const short8*)&XL[ 0 + c16][kk*32+g*8];
    short8 a1 = *(const short8*)&XL[16 + c16][kk*32+g*8];
    short8 a2 = *(const short8*)&XL[32 + c16][kk*32+g*8];
    short8 a3 = *(const short8*)&XL[48 + c16][kk*32+g*8];
    #pragma unroll
    for(int jj=0;jj<2;++jj){
      if(jl0+jj < jcount){
        int ji = jbase + jl0 + jj;
        short8 bf = ldg_frag(WiF + ((size_t)(ji*8+kk)*64 + lane)*8);
        acc[jj][0] = MFMA16(a0, bf, acc[jj][0]);
        acc[jj][1] = MFMA16(a1, bf, acc[jj][1]);
        acc[jj][2] = MFMA16(a2, bf, acc[jj][2]);
        acc[jj][3] = MFMA16(a3, bf, acc[jj][3]);
      }
    }
  }
  int mbase = rb*64;
  #pragma unroll
  for(int jj=0;jj<2;++jj){
    if(jl0+jj >= jcount) continue;
    int ji = jbase + jl0 + jj;
    if(ji < 32){                           // z -> silu -> zg
      int col = ji*16 + c16;
      #pragma unroll
      for(int li=0;li<4;li++){
        #pragma unroll
        for(int r2=0;r2<4;r2++)
          zg[(size_t)(mbase + li*16 + g*4 + r2)*512 + col] = f2bf(siluf(acc[jj][li][r2]));
      }
    } else if(ji < 72){                    // xBC raw (pre-conv), bf16
      int col = ji*16 + c16 - 512;
      #pragma unroll
      for(int li=0;li<4;li++){
        #pragma unroll
        for(int r2=0;r2<4;r2++)
          xbc[(size_t)(mbase + li*16 + g*4 + r2)*640 + col] = f2bf(acc[jj][li][r2]);
      }
    } else if(c16 < 8){                    // dt (cols 1152..1159)
      int hd = c16;
      float A = -expf(alog[hd]);
      float bias = dtb[hd];
      #pragma unroll
      for(int li=0;li<4;li++){
        #pragma unroll
        for(int r2=0;r2<4;r2++){
          int m = mbase + li*16 + g*4 + r2;
          float v = acc[jj][li][r2] + bias;
          float sp = (v>20.f)? v : log1pf(expf(v));
          dtp[(size_t)((m>>6)*8 + hd)*64 + (m&63)] = sp;
          dtA[(size_t)((m>>6)*8 + hd)*64 + (m&63)] = sp*A;
        }
      }
    }
  }
}

// ---------------- K1d: conv of B/C channels ONLY (orig cols 512..639), 4 senses ----------
__global__ __launch_bounds__(512) void k_convBC(const u16* __restrict__ xbc,
    const float* __restrict__ convw, const float* __restrict__ convb,
    u16* __restrict__ bH0, u16* __restrict__ bH1,
    u16* __restrict__ bV0, u16* __restrict__ bV1){
  int s = blockIdx.x, y = blockIdx.y;
  int dirb = y&1, dirV = y>>1;
  int t = threadIdx.x;
  int u = t>>3, cg = t&7;
  int b_ = s>>6, r_ = s&63;
  int cB = 512 + cg*8, cC = 576 + cg*8;
  float4 cwB[8], cwC[8]; float cbB[8], cbC[8];
  #pragma unroll
  for(int i=0;i<8;i++){
    cwB[i] = *(const float4*)(convw + (size_t)(cB+i)*4);
    cwC[i] = *(const float4*)(convw + (size_t)(cC+i)*4);
    cbB[i] = convb[cB+i]; cbC[i] = convb[cC+i];
  }
  BF8 wB[4], wC[4];
  #pragma unroll
  for(int j=0;j<4;j++){
    int p = u - 3 + j;                       // scan-coord window
    if(p >= 0){
      int m = dirb ? 63-p : p;
      size_t row = dirV ? ((size_t)b_*4096 + (size_t)m*64 + r_) : ((size_t)s*64 + m);
      wB[j].q = *(const uint4*)(xbc + row*640 + cB);
      wC[j].q = *(const uint4*)(xbc + row*640 + cC);
    } else { wB[j].q = (uint4){0u,0u,0u,0u}; wC[j].q = (uint4){0u,0u,0u,0u}; }
  }
  BF8 oB, oC;
  #pragma unroll
  for(int ch=0; ch<8; ++ch){
    float vB = cbB[ch] + cwB[ch].w*bf2f(wB[3].h[ch]) + cwB[ch].z*bf2f(wB[2].h[ch])
                       + cwB[ch].y*bf2f(wB[1].h[ch]) + cwB[ch].x*bf2f(wB[0].h[ch]);
    float vC = cbC[ch] + cwC[ch].w*bf2f(wC[3].h[ch]) + cwC[ch].z*bf2f(wC[2].h[ch])
                       + cwC[ch].y*bf2f(wC[1].h[ch]) + cwC[ch].x*bf2f(wC[0].h[ch]);
    oB.h[ch] = f2bf(siluf(vB));
    oC.h[ch] = f2bf(siluf(vC));
  }
  u16* dst = ((y==0)? bH0 : (y==1)? bH1 : (y==2)? bV0 : bV1) + ((size_t)(s*64+u))*128;
  *(uint4*)(dst + cg*8)      = oB.q;
  *(uint4*)(dst + 64 + cg*8) = oC.q;
}

// ---------------- K2: SSD scan, BOTH dirb senses per block; gate+RMSNorm fused ----------
// grid 512 1D XCD-swizzled: xcd=id&7, rem=id>>3 (0..63), s=xcd*32+(rem>>1), dirV=rem&1.
// 512 thr = 8 waves. Per dirb: prefix, G (bBC), stage+conv X (LDS), M-build, Y=M@X;
// then gate(zg)+RMSNorm, 0.5*nw*g*rs accumulated in 32 VGPRs across the two dirs.
// Writes SUMMED U (bf16) to UHs or UVs — halves U traffic vs per-variant buffers.
__global__ __launch_bounds__(512, 2) void k_scan2(
    const u16* __restrict__ xbc,
    const u16* __restrict__ bH0, const u16* __restrict__ bH1,
    const u16* __restrict__ bV0, const u16* __restrict__ bV1,
    const u16* __restrict__ zg,
    const float* __restrict__ convw, const float* __restrict__ convb,
    const float* __restrict__ dtp_g, const float* __restrict__ dtA_g,
    const float* __restrict__ dskip, const float* __restrict__ normw,
    u16* __restrict__ UHs, u16* __restrict__ UVs){
  // XV [64][520] 66560 | Gtri 8320 | sL 2048 | dtL 2048 | nwL 2048 = 81024 B
  __shared__ __align__(16) char smem[81024];
  u16 (*XV)[520] = (u16(*)[520])smem;
  float* Gtri = (float*)(smem + 66560);
  float* sL   = (float*)(smem + 74880);
  float* dtL  = (float*)(smem + 76928);
  float* nwL  = (float*)(smem + 78976);

  int id = blockIdx.x;
  int xcd = id & 7;
  int rem = id >> 3;                 // 0..63
  int s = xcd*32 + (rem>>1);
  int dirV = rem & 1;
  int t = threadIdx.x;
  int w = t>>6, lane = t&63, g = lane>>4, c16 = lane&15;
  int b_ = s>>6, r_ = s&63;
  float dsk = dskip[w];
  int c0 = lane*8;
  nwL[t] = normw[t];
  BF8 uacc[8];

  #pragma unroll 1
  for(int dirb=0; dirb<2; ++dirb){
    __syncthreads();   // protect XV/Gtri/sL/dtL from previous iteration readers
    const u16* xc = (dirV ? (dirb? bV1 : bV0) : (dirb? bH1 : bH0)) + (size_t)s*64*128;
    // ---- per-head prefix sum of dt*A in scan coords (wave-local) ----
    {
      int tt = dirb ? 63-lane : lane;
      size_t dti = dirV ? ((size_t)((b_*64 + tt)*8 + w))*64 + r_
                        : ((size_t)(s*8 + w))*64 + tt;
      float a = dtA_g[dti];
      float d = dtp_g[dti];
      #pragma unroll
      for(int off=1; off<64; off<<=1){
        float nb = __shfl_up(a, off, 64);
        if(lane >= off) a += nb;
      }
      sL[w*64+lane] = a;
      dtL[w*64+lane] = d;
    }
    // ---- G = C @ B^T from conv'd compact B/C; lower-tri stored ----
    #pragma unroll
    for(int tt2=0; tt2<2; ++tt2){
      int tile = 2*w + tt2, li = tile>>2, ji = tile&3;
      f32x4 acc = {0.f,0.f,0.f,0.f};
      #pragma unroll
      for(int kk=0; kk<2; ++kk){
        short8 af = ldg_frag(xc + (size_t)(li*16 + c16)*128 + 64 + kk*32 + g*8); // C rows
        short8 bf = ldg_frag(xc + (size_t)(ji*16 + c16)*128 +      kk*32 + g*8); // B rows
        acc = MFMA16(af, bf, acc);
      }
      int col = ji*16 + c16;
      #pragma unroll
      for(int r=0;r<4;r++){
        int row = li*16 + g*4 + r;
        if(col <= row) Gtri[(row*(row+1))/2 + col] = acc[r];
      }
    }
    // ---- stage RAW X (cols 0..511, scan order) into XV ----
    #pragma unroll
    for(int it=0; it<8; ++it){
      int tr = w + 8*it;
      int m = dirb ? 63-tr : tr;
      size_t row = dirV ? ((size_t)b_*4096 + (size_t)m*64 + r_) : ((size_t)s*64 + m);
      *(uint4*)&XV[tr][c0] = *(const uint4*)(xbc + row*640 + c0);
    }
    __syncthreads();
    // ---- conv X in LDS (scan-coord FIR), two-phase, strided rows ----
    {
      float4 cwx[8]; float cbx[8];
      #pragma unroll
      for(int i=0;i<8;i++){
        cwx[i] = *(const float4*)(convw + (size_t)(c0+i)*4);
        cbx[i] = convb[c0+i];
      }
      BF8 outr[8];
      #pragma unroll
      for(int it=0; it<8; ++it){
        int tr = w + 8*it;
        BF8 wnd[4];
        #pragma unroll
        for(int j=0;j<4;j++){
          int p = tr - 3 + j;
          if(p >= 0) wnd[j].q = *(const uint4*)&XV[p][c0];
          else       wnd[j].q = (uint4){0u,0u,0u,0u};
        }
        #pragma unroll
        for(int ch=0; ch<8; ++ch){
          float v = cbx[ch] + cwx[ch].w*bf2f(wnd[3].h[ch]) + cwx[ch].z*bf2f(wnd[2].h[ch])
                            + cwx[ch].y*bf2f(wnd[1].h[ch]) + cwx[ch].x*bf2f(wnd[0].h[ch]);
          outr[it].h[ch] = f2bf(siluf(v));
        }
      }
      __syncthreads();
      #pragma unroll
      for(int it=0; it<8; ++it)
        *(uint4*)&XV[w + 8*it][c0] = outr[it].q;
    }
    __syncthreads();
    // ---- X-frags preload (own head's 64 cols) ----
    short8 xfr[4][2];
    #pragma unroll
    for(int pi=0; pi<4; ++pi){
      #pragma unroll
      for(int kk=0; kk<2; ++kk){
        BF8 u;
        #pragma unroll
        for(int i=0;i<8;i++){
          int uu = kk*32 + g*8 + i;
          u.h[i] = XV[uu][w*64 + pi*16 + c16];
        }
        xfr[pi][kk] = u.v;
      }
    }
    // ---- per l-tile: build M fragments, Y = M@X, write raw Y (orig-l order) ----
    #pragma unroll 1
    for(int li=0; li<4; ++li){
      int tr = li*16 + c16;            // A-frag row (scan coord)
      float sl = sL[w*64 + tr];
      int tb = (tr*(tr+1))/2;
      short8 mfr[2];
      #pragma unroll
      for(int kk=0; kk<2; ++kk){
        BF8 u;
        #pragma unroll
        for(int i=0;i<8;i++){
          int uu = kk*32 + g*8 + i;
          float m = 0.f;
          if(uu <= tr){
            m = __expf(sl - sL[w*64+uu]) * dtL[w*64+uu] * Gtri[tb + uu];
            if(uu == tr) m += dsk;     // Dskip folded into diagonal (exact)
          }
          u.h[i] = f2bf(m);
        }
        mfr[kk] = u.v;
      }
      #pragma unroll
      for(int pi=0; pi<4; ++pi){
        f32x4 acc = {0.f,0.f,0.f,0.f};
        acc = MFMA16(mfr[0], xfr[pi][0], acc);
        acc = MFMA16(mfr[1], xfr[pi][1], acc);
        #pragma unroll
        for(int r=0;r<4;r++){
          int trow = li*16 + g*4 + r;
          int lorig = dirb ? 63-trow : trow;
          XV[lorig][w*64 + pi*16 + c16] = f2bf(acc[r]);
        }
      }
    }
    __syncthreads();
    // ---- gate * zg, RMSNorm per row, accumulate 0.5*nw*g*rs into uacc ----
    #pragma unroll 1
    for(int rr=0; rr<8; ++rr){
      int l = w*8 + rr;
      size_t zrow = dirV ? ((size_t)b_*4096 + (size_t)l*64 + r_) : ((size_t)s*64 + l);
      BF8 yv, z8;
      yv.q = *(const uint4*)&XV[l][c0];
      z8.q = *(const uint4*)(zg + zrow*512 + c0);
      float gv[8]; float ss = 0.f;
      #pragma unroll
      for(int i=0;i<8;i++){ gv[i] = bf2f(yv.h[i]) * bf2f(z8.h[i]); ss += gv[i]*gv[i]; }
      #pragma unroll
      for(int off=32; off>=1; off>>=1) ss += __shfl_xor(ss, off, 64);
      float rs = rsqrtf(ss*(1.f/512.f) + EPSF);
      if(dirb==0){
        #pragma unroll
        for(int i=0;i<8;i++) uacc[rr].h[i] = f2bf(0.5f*gv[i]*rs*nwL[c0+i]);
      } else {
        #pragma unroll
        for(int i=0;i<8;i++)
          uacc[rr].h[i] = f2bf(bf2f(uacc[rr].h[i]) + 0.5f*gv[i]*rs*nwL[c0+i]);
      }
    }
  }
  // ---- write summed U (coalesced) ----
  u16* un = (dirV ? UVs : UHs) + (size_t)s*64*512;
  #pragma unroll
  for(int rr=0; rr<8; ++rr){
    int l = w*8 + rr;
    *(uint4*)(un + (size_t)l*512 + c0) = uacc[rr].q;
  }
}

// ---------------- K3: blend (2 pre-normed U streams) + Wcomb GEMM + stats ----------------
// grid 256 = (bb,h); block 1024 = 16 waves; wave wv loads rows wv+16i and owns o-tile wv.
__global__ __launch_bounds__(1024, 4) void k_blendfinal(
    const u16* __restrict__ UHs, const u16* __restrict__ UVs,
    const float* __restrict__ Q1, const float* __restrict__ Sx,
    const u16* __restrict__ WCF,
    float* __restrict__ out, float* __restrict__ stats){
  __shared__ u16 A[64][520];
  __shared__ float asL[64], bsL[64];
  __shared__ float red[2][16];
  int blk = blockIdx.x; int bb = blk>>6, h = blk&63;
  int t = threadIdx.x;
  if(t<64){
    float qv = Q1[bb*4096 + h*64 + t];
    float sv = Sx[bb*4096 + h*64 + t];
    float al = sigf(qv);
    float sc = 0.5f + 0.5f*sv;
    asL[t] = al*sc; bsL[t] = (1.f-al)*sc;
  }
  __syncthreads();
  int wv = t>>6, lane = t&63, g = lane>>4, c16 = lane&15;
  #pragma unroll
  for(int i=0;i<4;i++){
    int wp = wv + 16*i;
    int c8 = lane*8;
    size_t rH = ((size_t)((bb*64+h)*64 + wp))*512 + c8;
    size_t rV = ((size_t)((bb*64+wp)*64 + h))*512 + c8;
    BF8 uh, uv, o;
    uh.q = *(const uint4*)(UHs + rH);
    uv.q = *(const uint4*)(UVs + rV);
    float aw = asL[wp], bw = bsL[wp];
    #pragma unroll
    for(int j=0;j<8;j++)
      o.h[j] = f2bf(aw*bf2f(uh.h[j]) + bw*bf2f(uv.h[j]));
    *(uint4*)&A[wp][c8] = o.q;
  }
  __syncthreads();
  int ci = wv;
  f32x4 acc0={0.f,0.f,0.f,0.f}, acc1=acc0, acc2=acc0, acc3=acc0;
  #pragma unroll 2
  for(int kk=0; kk<16; ++kk){
    short8 bfr = ldg_frag(WCF + (size_t)((((ci*16+kk)*4+g)*16+c16)*8));
    short8 a0 = *(const short8*)&A[ 0+c16][kk*32+g*8];
    short8 a1 = *(const short8*)&A[16+c16][kk*32+g*8];
    short8 a2 = *(const short8*)&A[32+c16][kk*32+g*8];
    short8 a3 = *(const short8*)&A[48+c16][kk*32+g*8];
    acc0 = MFMA16(a0,bfr,acc0); acc1 = MFMA16(a1,bfr,acc1);
    acc2 = MFMA16(a2,bfr,acc2); acc3 = MFMA16(a3,bfr,acc3);
  }
  float s1=0.f, s2=0.f;
  int o_ = ci*16 + c16;
  #pragma unroll
  for(int li=0; li<4; ++li){
    f32x4 a = (li==0)?acc0 : (li==1)?acc1 : (li==2)?acc2 : acc3;
    int w0 = li*16 + g*4;
    float4 vv = {a[0], a[1], a[2], a[3]};
    s1 += (vv.x+vv.y)+(vv.z+vv.w);
    s2 += (vv.x*vv.x+vv.y*vv.y)+(vv.z*vv.z+vv.w*vv.w);
    *(float4*)(out + (((size_t)(bb*256+o_)*64 + h)*64 + w0)) = vv;
  }
  #pragma unroll
  for(int off=32;off>=1;off>>=1){ s1+=__shfl_xor(s1,off,64); s2+=__shfl_xor(s2,off,64); }
  if(lane==0){ red[0][wv]=s1; red[1][wv]=s2; }
  __syncthreads();
  if(t==0){
    float a=0.f,b=0.f;
    #pragma unroll
    for(int i=0;i<16;i++){ a+=red[0][i]; b+=red[1][i]; }
    stats[blk*2+0]=a; stats[blk*2+1]=b;
  }
}

// ---------------- K4: per-batch global norm + exact GELU, in place on d_out ----------------
__global__ __launch_bounds__(256) void k_final(float* __restrict__ out,
    const float* __restrict__ stats, const float* __restrict__ gg,
    const float* __restrict__ gb){
  __shared__ float red[64][2];
  __shared__ float mv[2];
  int blk = blockIdx.x; int bb = blk>>6, h = blk&63;
  int t = threadIdx.x;
  if(t<64){ red[t][0] = stats[(bb*64+t)*2+0]; red[t][1] = stats[(bb*64+t)*2+1]; }
  __syncthreads();
  if(t==0){
    float s1=0.f,s2=0.f;
    for(int i=0;i<64;i++){ s1+=red[i][0]; s2+=red[i][1]; }
    float mu = s1*(1.f/1048576.f);
    float var = s2*(1.f/1048576.f) - mu*mu;
    mv[0]=mu; mv[1]=rsqrtf(var+EPSF);
  }
  __syncthreads();
  float mu = mv[0], rs = mv[1];
  for(int i=0;i<64;i++){ int idx=t+256*i; int o=idx>>6, w=idx&63;
    size_t gidx = (size_t)((bb*256+o)*64+h)*64+w;
    float v = out[gidx];
    float yn = (v-mu)*rs*gg[o] + gb[o];
    out[gidx] = 0.5f*yn*(1.f+erff(yn*0.70710678118654752f));
  }
}

extern "C" void kernel_launch(void* const* d_in, const int* in_sizes, int n_in,
                              void* d_out, int out_size, void* d_ws, size_t ws_size,
                              hipStream_t stream) {
  const float* x     = (const float*)d_in[0];
  const float* Q1    = (const float*)d_in[1];
  // d_in[2] = Q2 : unused by the reference
  const float* Sx    = (const float*)d_in[3];
  const float* lng   = (const float*)d_in[4];
  const float* lnb   = (const float*)d_in[5];
  const float* Wi    = (const float*)d_in[6];
  const float* convw = (const float*)d_in[7];
  const float* convb = (const float*)d_in[8];
  const float* dtb   = (const float*)d_in[9];
  const float* alog  = (const float*)d_in[10];
  const float* dskip = (const float*)d_in[11];
  const float* normw = (const float*)d_in[12];
  const float* Wo    = (const float*)d_in[13];
  const float* gg    = (const float*)d_in[14];
  const float* gb    = (const float*)d_in[15];
  const float* W1    = (const float*)d_in[16];
  float* out = (float*)d_out;
  char* ws = (char*)d_ws;

  // ws layout (~94 MiB; ws_size = 256 MiB)
  size_t o = 0;
  u16*   xnb  = (u16*)(ws + o);  o += (size_t)16384*256*2;        // 8 MB  xn bf16
  u16*   zgb  = (u16*)(ws + o);  o += (size_t)16384*512*2;        // 16 MB
  u16*   xbc  = (u16*)(ws + o);  o += (size_t)16384*640*2;        // 20 MB raw xBC
  u16*   bH0  = (u16*)(ws + o);  o += (size_t)16384*128*2;        // 4 MB conv'd B/C
  u16*   bH1  = (u16*)(ws + o);  o += (size_t)16384*128*2;        // 4 MB
  u16*   bV0  = (u16*)(ws + o);  o += (size_t)16384*128*2;        // 4 MB
  u16*   bV1  = (u16*)(ws + o);  o += (size_t)16384*128*2;        // 4 MB
  u16*   UHs  = (u16*)(ws + o);  o += (size_t)16384*512*2;        // 16 MB (summed dirs)
  u16*   UVs  = (u16*)(ws + o);  o += (size_t)16384*512*2;        // 16 MB
  float* dtp  = (float*)(ws + o); o += (size_t)131072*4;          // 0.5 MB
  float* dtA  = (float*)(ws + o); o += (size_t)131072*4;          // 0.5 MB
  float* stats= (float*)(ws + o); o += 4096;
  u16*   WiF  = (u16*)(ws + o);  o += (size_t)73*8*64*8*2;        // 584 KB
  u16*   WCF  = (u16*)(ws + o);  o += (size_t)16384*8*2;          // 256 KB

  k_ln<<<256, 256, 0, stream>>>(x, lng, lnb, xnb);
  k_prep<<<658, 256, 0, stream>>>(Wi, WiF, Wo, W1, WCF);
  k_gemm_in<<<1280, 512, 0, stream>>>(xnb, WiF, dtb, alog,
                                      zgb, xbc, dtp, dtA);
  k_convBC<<<dim3(256,4), 512, 0, stream>>>(xbc, convw, convb, bH0, bH1, bV0, bV1);
  k_scan2<<<512, 512, 0, stream>>>(xbc, bH0, bH1, bV0, bV1, zgb, convw, convb,
                                   dtp, dtA, dskip, normw, UHs, UVs);
  k_blendfinal<<<256, 1024, 0, stream>>>(UHs, UVs, Q1, Sx, WCF, out, stats);
  k_final<<<256, 256, 0, stream>>>(out, stats, gg, gb);
}

// Round 20
// 208.766 us; speedup vs baseline: 1.0003x; 1.0003x over previous
//
#include <hip/hip_runtime.h>
#include <hip/hip_bf16.h>

// Problem constants (B,DIM,H,W)=(4,256,64,64), DSTATE=64, EXPAND=2, DCONV=4
// DINNER=512, HEADDIM=64, NHEADS=8, DINPROJ=1160, CONVDIM=640, EPS=1e-5
#define EPSF 1e-5f

typedef unsigned short u16;
typedef __attribute__((ext_vector_type(8))) short short8;   // 8 x bf16 MFMA operand
typedef __attribute__((ext_vector_type(4))) float f32x4;    // MFMA accumulator

__device__ __forceinline__ float sigf(float x){ return 1.f/(1.f+__expf(-x)); }
__device__ __forceinline__ float siluf(float x){ return x/(1.f+__expf(-x)); }
__device__ __forceinline__ u16 f2bf(float x){ __hip_bfloat16 h = __float2bfloat16(x); return *reinterpret_cast<u16*>(&h); }
__device__ __forceinline__ float bf2f(u16 u){ __hip_bfloat16 h; *reinterpret_cast<u16*>(&h) = u; return __bfloat162float(h); }

union BF8 { short8 v; u16 h[8]; uint4 q; };

__device__ __forceinline__ short8 ldg_frag(const u16* p){
  BF8 u; u.q = *(const uint4*)p; return u.v;
}
#define MFMA16(a,b,c) __builtin_amdgcn_mfma_f32_16x16x32_bf16((a),(b),(c),0,0,0)

// ---------------- K0: channel LayerNorm, x (B,C,H,W) -> xn bf16 (B,H,W,C) ----------------
__global__ __launch_bounds__(256) void k_ln(const float* __restrict__ x,
                                            const float* __restrict__ g,
                                            const float* __restrict__ b,
                                            u16* __restrict__ xn){
  __shared__ float XL[256][65];
  __shared__ float red[2][4][64];
  __shared__ float muL[64], rsL[64];
  int blk = blockIdx.x; int bb = blk>>6, h = blk&63;
  int t = threadIdx.x;
  const float* xb = x + ((size_t)bb*256*4096) + h*64;
  for(int i=0;i<64;i++){ int idx = t + 256*i; int c = idx>>6, w = idx&63;
    XL[c][w] = xb[(size_t)c*4096 + w]; }
  __syncthreads();
  { int w = t & 63, q = t >> 6;
    float s1=0, s2=0;
    for(int c=q*64;c<q*64+64;c++){ float v = XL[c][w]; s1+=v; s2+=v*v; }
    red[0][q][w]=s1; red[1][q][w]=s2; }
  __syncthreads();
  if(t<64){ float a=0,c2=0;
    for(int q=0;q<4;q++){a+=red[0][q][t]; c2+=red[1][q][t];}
    float mu=a*(1.f/256.f); float var=c2*(1.f/256.f)-mu*mu;
    muL[t]=mu; rsL[t]=rsqrtf(var+EPSF); }
  __syncthreads();
  u16* xnb = xn + (size_t)(bb*64+h)*64*256;
  for(int i=0;i<64;i++){ int idx = t + 256*i; int w = idx>>8, c = idx&255;
    float v = (XL[c][w]-muL[w])*rsL[w]*g[c]+b[c];
    xnb[w*256 + c] = f2bf(v); }
}

// ---------------- K_prep: pack Wi frags (blocks 0..145) + Wcomb=Wo@W1^T (blocks 146..657) ----
__global__ __launch_bounds__(256) void k_prep(const float* __restrict__ Wi,
                                              u16* __restrict__ WiF,
                                              const float* __restrict__ Wo,
                                              const float* __restrict__ W1,
                                              u16* __restrict__ WCF){
  __shared__ float WoL[256];
  int blk = blockIdx.x;
  int t = threadIdx.x;
  if(blk < 146){
    int f = blk*256 + t;                  // 37376 threads exactly
    int lane = f & 63, kk = (f>>6)&7, ji = f>>9;
    int g = lane>>4, c16 = lane&15;
    int j = ji*16 + c16;
    BF8 o;
    #pragma unroll
    for(int i=0;i<8;i++){
      int k = kk*32 + g*8 + i;
      o.h[i] = (j < 1160) ? f2bf(Wi[(size_t)k*1160 + j]) : (u16)0;
    }
    *(uint4*)(WiF + (size_t)f*8) = o.q;
  } else {
    int k = blk - 146;                    // 0..511
    int o = t;                            // 0..255
    WoL[o] = Wo[(size_t)k*256 + o];
    __syncthreads();
    const float4* w1p = (const float4*)(W1 + (size_t)o*256);
    const float4* wop = (const float4*)WoL;
    float d = 0.f;
    #pragma unroll 8
    for(int i=0;i<64;i++){
      float4 a = wop[i]; float4 b = w1p[i];
      d += a.x*b.x + a.y*b.y + a.z*b.z + a.w*b.w;
    }
    int kk = k>>5, g = (k>>3)&3, i2 = k&7;
    int ci = o>>4, c16 = o&15;
    WCF[(size_t)((((ci*16+kk)*4+g)*16+c16)*8 + i2)] = f2bf(d);
  }
}

// ---------------- K1: in-projection GEMM (once; direction-independent) ----------------
// grid 1280 1D, XCD-swizzled so the 5 col-chunk blocks of each row-block share one XCD L2.
__global__ __launch_bounds__(512, 4) void k_gemm_in(const u16* __restrict__ xn,
    const u16* __restrict__ WiF, const float* __restrict__ dtb,
    const float* __restrict__ alog,
    u16* __restrict__ zg, u16* __restrict__ xbc,
    float* __restrict__ dtp, float* __restrict__ dtA){
  __shared__ u16 XL[64][264];     // A tile 64x256 bf16, pad 264 (33.8 KB)
  int id = blockIdx.x;
  int xcd = id & 7;
  int rem = id >> 3;              // 0..159
  int rb_local = rem / 5;
  int cb = rem - rb_local*5;
  int rb = xcd*32 + rb_local;
  int t = threadIdx.x;
  int w = t>>6, lane = t&63, g = lane>>4, c16 = lane&15;

  const u16* asrc = xn + (size_t)rb*64*256;
  #pragma unroll
  for(int i=0;i<4;i++){
    int idx = t + 512*i;
    int row = idx>>5, ch = idx&31;
    *(uint4*)&XL[row][ch*8] = *(const uint4*)(asrc + (size_t)row*256 + ch*8);
  }
  __syncthreads();

  int jbase = cb*15;
  int jcount = (cb==4) ? 13 : 15;
  int jl0 = w*2;

  f32x4 acc[2][4];
  #pragma unroll
  for(int jj=0;jj<2;jj++){
    #pragma unroll
    for(int li=0;li<4;li++) acc[jj][li] = (f32x4){0.f,0.f,0.f,0.f};
  }
  #pragma unroll
  for(int kk=0;kk<8;++kk){
    short8 a0 = *(const short8*)&XL[ 0 + c16][kk*32+g*8];
    short8 a1 = *(const short8*)&XL[16 + c16][kk*32+g*8];
    short8 a2 = *(const short8*)&XL[32 + c16][kk*32+g*8];
    short8 a3 = *(const short8*)&XL[48 + c16][kk*32+g*8];
    #pragma unroll
    for(int jj=0;jj<2;++jj){
      if(jl0+jj < jcount){
        int ji = jbase + jl0 + jj;
        short8 bf = ldg_frag(WiF + ((size_t)(ji*8+kk)*64 + lane)*8);
        acc[jj][0] = MFMA16(a0, bf, acc[jj][0]);
        acc[jj][1] = MFMA16(a1, bf, acc[jj][1]);
        acc[jj][2] = MFMA16(a2, bf, acc[jj][2]);
        acc[jj][3] = MFMA16(a3, bf, acc[jj][3]);
      }
    }
  }
  int mbase = rb*64;
  #pragma unroll
  for(int jj=0;jj<2;++jj){
    if(jl0+jj >= jcount) continue;
    int ji = jbase + jl0 + jj;
    if(ji < 32){                           // z -> silu -> zg
      int col = ji*16 + c16;
      #pragma unroll
      for(int li=0;li<4;li++){
        #pragma unroll
        for(int r2=0;r2<4;r2++)
          zg[(size_t)(mbase + li*16 + g*4 + r2)*512 + col] = f2bf(siluf(acc[jj][li][r2]));
      }
    } else if(ji < 72){                    // xBC raw (pre-conv), bf16
      int col = ji*16 + c16 - 512;
      #pragma unroll
      for(int li=0;li<4;li++){
        #pragma unroll
        for(int r2=0;r2<4;r2++)
          xbc[(size_t)(mbase + li*16 + g*4 + r2)*640 + col] = f2bf(acc[jj][li][r2]);
      }
    } else if(c16 < 8){                    // dt (cols 1152..1159)
      int hd = c16;
      float A = -expf(alog[hd]);
      float bias = dtb[hd];
      #pragma unroll
      for(int li=0;li<4;li++){
        #pragma unroll
        for(int r2=0;r2<4;r2++){
          int m = mbase + li*16 + g*4 + r2;
          float v = acc[jj][li][r2] + bias;
          float sp = (v>20.f)? v : log1pf(expf(v));
          dtp[(size_t)((m>>6)*8 + hd)*64 + (m&63)] = sp;
          dtA[(size_t)((m>>6)*8 + hd)*64 + (m&63)] = sp*A;
        }
      }
    }
  }
}

// ---------------- K1d: conv of B/C channels ONLY (orig cols 512..639), 4 senses ----------
__global__ __launch_bounds__(512) void k_convBC(const u16* __restrict__ xbc,
    const float* __restrict__ convw, const float* __restrict__ convb,
    u16* __restrict__ bH0, u16* __restrict__ bH1,
    u16* __restrict__ bV0, u16* __restrict__ bV1){
  int s = blockIdx.x, y = blockIdx.y;
  int dirb = y&1, dirV = y>>1;
  int t = threadIdx.x;
  int u = t>>3, cg = t&7;
  int b_ = s>>6, r_ = s&63;
  int cB = 512 + cg*8, cC = 576 + cg*8;
  float4 cwB[8], cwC[8]; float cbB[8], cbC[8];
  #pragma unroll
  for(int i=0;i<8;i++){
    cwB[i] = *(const float4*)(convw + (size_t)(cB+i)*4);
    cwC[i] = *(const float4*)(convw + (size_t)(cC+i)*4);
    cbB[i] = convb[cB+i]; cbC[i] = convb[cC+i];
  }
  BF8 wB[4], wC[4];
  #pragma unroll
  for(int j=0;j<4;j++){
    int p = u - 3 + j;                       // scan-coord window
    if(p >= 0){
      int m = dirb ? 63-p : p;
      size_t row = dirV ? ((size_t)b_*4096 + (size_t)m*64 + r_) : ((size_t)s*64 + m);
      wB[j].q = *(const uint4*)(xbc + row*640 + cB);
      wC[j].q = *(const uint4*)(xbc + row*640 + cC);
    } else { wB[j].q = (uint4){0u,0u,0u,0u}; wC[j].q = (uint4){0u,0u,0u,0u}; }
  }
  BF8 oB, oC;
  #pragma unroll
  for(int ch=0; ch<8; ++ch){
    float vB = cbB[ch] + cwB[ch].w*bf2f(wB[3].h[ch]) + cwB[ch].z*bf2f(wB[2].h[ch])
                       + cwB[ch].y*bf2f(wB[1].h[ch]) + cwB[ch].x*bf2f(wB[0].h[ch]);
    float vC = cbC[ch] + cwC[ch].w*bf2f(wC[3].h[ch]) + cwC[ch].z*bf2f(wC[2].h[ch])
                       + cwC[ch].y*bf2f(wC[1].h[ch]) + cwC[ch].x*bf2f(wC[0].h[ch]);
    oB.h[ch] = f2bf(siluf(vB));
    oC.h[ch] = f2bf(siluf(vC));
  }
  u16* dst = ((y==0)? bH0 : (y==1)? bH1 : (y==2)? bV0 : bV1) + ((size_t)(s*64+u))*128;
  *(uint4*)(dst + cg*8)      = oB.q;
  *(uint4*)(dst + 64 + cg*8) = oC.q;
}

// ---------------- K2: SSD scan, BOTH dirb senses per block; gate+RMSNorm fused ----------
// grid 512 1D XCD-swizzled: xcd=id&7, rem=id>>3 (0..63), s=xcd*32+(rem>>1), dirV=rem&1.
// 512 thr = 8 waves. Per dirb: prefix, G (bBC), stage+conv X (LDS), M-build, Y=M@X;
// then gate(zg)+RMSNorm, 0.5*nw*g*rs accumulated in 32 VGPRs across the two dirs.
// Writes SUMMED U (bf16) to UHs or UVs — halves U traffic vs per-variant buffers.
__global__ __launch_bounds__(512, 2) void k_scan2(
    const u16* __restrict__ xbc,
    const u16* __restrict__ bH0, const u16* __restrict__ bH1,
    const u16* __restrict__ bV0, const u16* __restrict__ bV1,
    const u16* __restrict__ zg,
    const float* __restrict__ convw, const float* __restrict__ convb,
    const float* __restrict__ dtp_g, const float* __restrict__ dtA_g,
    const float* __restrict__ dskip, const float* __restrict__ normw,
    u16* __restrict__ UHs, u16* __restrict__ UVs){
  // XV [64][520] 66560 | Gtri 8320 | sL 2048 | dtL 2048 | nwL 2048 = 81024 B
  __shared__ __align__(16) char smem[81024];
  u16 (*XV)[520] = (u16(*)[520])smem;
  float* Gtri = (float*)(smem + 66560);
  float* sL   = (float*)(smem + 74880);
  float* dtL  = (float*)(smem + 76928);
  float* nwL  = (float*)(smem + 78976);

  int id = blockIdx.x;
  int xcd = id & 7;
  int rem = id >> 3;                 // 0..63
  int s = xcd*32 + (rem>>1);
  int dirV = rem & 1;
  int t = threadIdx.x;
  int w = t>>6, lane = t&63, g = lane>>4, c16 = lane&15;
  int b_ = s>>6, r_ = s&63;
  float dsk = dskip[w];
  int c0 = lane*8;
  nwL[t] = normw[t];
  BF8 uacc[8];

  #pragma unroll 1
  for(int dirb=0; dirb<2; ++dirb){
    __syncthreads();   // protect XV/Gtri/sL/dtL from previous iteration readers
    const u16* xc = (dirV ? (dirb? bV1 : bV0) : (dirb? bH1 : bH0)) + (size_t)s*64*128;
    // ---- per-head prefix sum of dt*A in scan coords (wave-local) ----
    {
      int tt = dirb ? 63-lane : lane;
      size_t dti = dirV ? ((size_t)((b_*64 + tt)*8 + w))*64 + r_
                        : ((size_t)(s*8 + w))*64 + tt;
      float a = dtA_g[dti];
      float d = dtp_g[dti];
      #pragma unroll
      for(int off=1; off<64; off<<=1){
        float nb = __shfl_up(a, off, 64);
        if(lane >= off) a += nb;
      }
      sL[w*64+lane] = a;
      dtL[w*64+lane] = d;
    }
    // ---- G = C @ B^T from conv'd compact B/C; lower-tri stored ----
    #pragma unroll
    for(int tt2=0; tt2<2; ++tt2){
      int tile = 2*w + tt2, li = tile>>2, ji = tile&3;
      f32x4 acc = {0.f,0.f,0.f,0.f};
      #pragma unroll
      for(int kk=0; kk<2; ++kk){
        short8 af = ldg_frag(xc + (size_t)(li*16 + c16)*128 + 64 + kk*32 + g*8); // C rows
        short8 bf = ldg_frag(xc + (size_t)(ji*16 + c16)*128 +      kk*32 + g*8); // B rows
        acc = MFMA16(af, bf, acc);
      }
      int col = ji*16 + c16;
      #pragma unroll
      for(int r=0;r<4;r++){
        int row = li*16 + g*4 + r;
        if(col <= row) Gtri[(row*(row+1))/2 + col] = acc[r];
      }
    }
    // ---- stage RAW X (cols 0..511, scan order) into XV ----
    #pragma unroll
    for(int it=0; it<8; ++it){
      int tr = w + 8*it;
      int m = dirb ? 63-tr : tr;
      size_t row = dirV ? ((size_t)b_*4096 + (size_t)m*64 + r_) : ((size_t)s*64 + m);
      *(uint4*)&XV[tr][c0] = *(const uint4*)(xbc + row*640 + c0);
    }
    __syncthreads();
    // ---- conv X in LDS (scan-coord FIR), two-phase, strided rows ----
    {
      float4 cwx[8]; float cbx[8];
      #pragma unroll
      for(int i=0;i<8;i++){
        cwx[i] = *(const float4*)(convw + (size_t)(c0+i)*4);
        cbx[i] = convb[c0+i];
      }
      BF8 outr[8];
      #pragma unroll
      for(int it=0; it<8; ++it){
        int tr = w + 8*it;
        BF8 wnd[4];
        #pragma unroll
        for(int j=0;j<4;j++){
          int p = tr - 3 + j;
          if(p >= 0) wnd[j].q = *(const uint4*)&XV[p][c0];
          else       wnd[j].q = (uint4){0u,0u,0u,0u};
        }
        #pragma unroll
        for(int ch=0; ch<8; ++ch){
          float v = cbx[ch] + cwx[ch].w*bf2f(wnd[3].h[ch]) + cwx[ch].z*bf2f(wnd[2].h[ch])
                            + cwx[ch].y*bf2f(wnd[1].h[ch]) + cwx[ch].x*bf2f(wnd[0].h[ch]);
          outr[it].h[ch] = f2bf(siluf(v));
        }
      }
      __syncthreads();
      #pragma unroll
      for(int it=0; it<8; ++it)
        *(uint4*)&XV[w + 8*it][c0] = outr[it].q;
    }
    __syncthreads();
    // ---- X-frags preload (own head's 64 cols) ----
    short8 xfr[4][2];
    #pragma unroll
    for(int pi=0; pi<4; ++pi){
      #pragma unroll
      for(int kk=0; kk<2; ++kk){
        BF8 u;
        #pragma unroll
        for(int i=0;i<8;i++){
          int uu = kk*32 + g*8 + i;
          u.h[i] = XV[uu][w*64 + pi*16 + c16];
        }
        xfr[pi][kk] = u.v;
      }
    }
    // ---- per l-tile: build M fragments, Y = M@X, write raw Y (orig-l order) ----
    #pragma unroll 1
    for(int li=0; li<4; ++li){
      int tr = li*16 + c16;            // A-frag row (scan coord)
      float sl = sL[w*64 + tr];
      int tb = (tr*(tr+1))/2;
      short8 mfr[2];
      #pragma unroll
      for(int kk=0; kk<2; ++kk){
        BF8 u;
        #pragma unroll
        for(int i=0;i<8;i++){
          int uu = kk*32 + g*8 + i;
          float m = 0.f;
          if(uu <= tr){
            m = __expf(sl - sL[w*64+uu]) * dtL[w*64+uu] * Gtri[tb + uu];
            if(uu == tr) m += dsk;     // Dskip folded into diagonal (exact)
          }
          u.h[i] = f2bf(m);
        }
        mfr[kk] = u.v;
      }
      #pragma unroll
      for(int pi=0; pi<4; ++pi){
        f32x4 acc = {0.f,0.f,0.f,0.f};
        acc = MFMA16(mfr[0], xfr[pi][0], acc);
        acc = MFMA16(mfr[1], xfr[pi][1], acc);
        #pragma unroll
        for(int r=0;r<4;r++){
          int trow = li*16 + g*4 + r;
          int lorig = dirb ? 63-trow : trow;
          XV[lorig][w*64 + pi*16 + c16] = f2bf(acc[r]);
        }
      }
    }
    __syncthreads();
    // ---- gate * zg, RMSNorm per row, accumulate 0.5*nw*g*rs into uacc ----
    #pragma unroll 1
    for(int rr=0; rr<8; ++rr){
      int l = w*8 + rr;
      size_t zrow = dirV ? ((size_t)b_*4096 + (size_t)l*64 + r_) : ((size_t)s*64 + l);
      BF8 yv, z8;
      yv.q = *(const uint4*)&XV[l][c0];
      z8.q = *(const uint4*)(zg + zrow*512 + c0);
      float gv[8]; float ss = 0.f;
      #pragma unroll
      for(int i=0;i<8;i++){ gv[i] = bf2f(yv.h[i]) * bf2f(z8.h[i]); ss += gv[i]*gv[i]; }
      #pragma unroll
      for(int off=32; off>=1; off>>=1) ss += __shfl_xor(ss, off, 64);
      float rs = rsqrtf(ss*(1.f/512.f) + EPSF);
      if(dirb==0){
        #pragma unroll
        for(int i=0;i<8;i++) uacc[rr].h[i] = f2bf(0.5f*gv[i]*rs*nwL[c0+i]);
      } else {
        #pragma unroll
        for(int i=0;i<8;i++)
          uacc[rr].h[i] = f2bf(bf2f(uacc[rr].h[i]) + 0.5f*gv[i]*rs*nwL[c0+i]);
      }
    }
  }
  // ---- write summed U (coalesced) ----
  u16* un = (dirV ? UVs : UHs) + (size_t)s*64*512;
  #pragma unroll
  for(int rr=0; rr<8; ++rr){
    int l = w*8 + rr;
    *(uint4*)(un + (size_t)l*512 + c0) = uacc[rr].q;
  }
}

// ---------------- K3: blend (2 pre-normed U streams) + Wcomb GEMM + stats ----------------
// grid 256 = (bb,h); block 1024 = 16 waves; wave wv loads rows wv+16i and owns o-tile wv.
__global__ __launch_bounds__(1024, 4) void k_blendfinal(
    const u16* __restrict__ UHs, const u16* __restrict__ UVs,
    const float* __restrict__ Q1, const float* __restrict__ Sx,
    const u16* __restrict__ WCF,
    float* __restrict__ out, float* __restrict__ stats){
  __shared__ u16 A[64][520];
  __shared__ float asL[64], bsL[64];
  __shared__ float red[2][16];
  int blk = blockIdx.x; int bb = blk>>6, h = blk&63;
  int t = threadIdx.x;
  if(t<64){
    float qv = Q1[bb*4096 + h*64 + t];
    float sv = Sx[bb*4096 + h*64 + t];
    float al = sigf(qv);
    float sc = 0.5f + 0.5f*sv;
    asL[t] = al*sc; bsL[t] = (1.f-al)*sc;
  }
  __syncthreads();
  int wv = t>>6, lane = t&63, g = lane>>4, c16 = lane&15;
  #pragma unroll
  for(int i=0;i<4;i++){
    int wp = wv + 16*i;
    int c8 = lane*8;
    size_t rH = ((size_t)((bb*64+h)*64 + wp))*512 + c8;
    size_t rV = ((size_t)((bb*64+wp)*64 + h))*512 + c8;
    BF8 uh, uv, o;
    uh.q = *(const uint4*)(UHs + rH);
    uv.q = *(const uint4*)(UVs + rV);
    float aw = asL[wp], bw = bsL[wp];
    #pragma unroll
    for(int j=0;j<8;j++)
      o.h[j] = f2bf(aw*bf2f(uh.h[j]) + bw*bf2f(uv.h[j]));
    *(uint4*)&A[wp][c8] = o.q;
  }
  __syncthreads();
  int ci = wv;
  f32x4 acc0={0.f,0.f,0.f,0.f}, acc1=acc0, acc2=acc0, acc3=acc0;
  #pragma unroll 2
  for(int kk=0; kk<16; ++kk){
    short8 bfr = ldg_frag(WCF + (size_t)((((ci*16+kk)*4+g)*16+c16)*8));
    short8 a0 = *(const short8*)&A[ 0+c16][kk*32+g*8];
    short8 a1 = *(const short8*)&A[16+c16][kk*32+g*8];
    short8 a2 = *(const short8*)&A[32+c16][kk*32+g*8];
    short8 a3 = *(const short8*)&A[48+c16][kk*32+g*8];
    acc0 = MFMA16(a0,bfr,acc0); acc1 = MFMA16(a1,bfr,acc1);
    acc2 = MFMA16(a2,bfr,acc2); acc3 = MFMA16(a3,bfr,acc3);
  }
  float s1=0.f, s2=0.f;
  int o_ = ci*16 + c16;
  #pragma unroll
  for(int li=0; li<4; ++li){
    f32x4 a = (li==0)?acc0 : (li==1)?acc1 : (li==2)?acc2 : acc3;
    int w0 = li*16 + g*4;
    float4 vv = {a[0], a[1], a[2], a[3]};
    s1 += (vv.x+vv.y)+(vv.z+vv.w);
    s2 += (vv.x*vv.x+vv.y*vv.y)+(vv.z*vv.z+vv.w*vv.w);
    *(float4*)(out + (((size_t)(bb*256+o_)*64 + h)*64 + w0)) = vv;
  }
  #pragma unroll
  for(int off=32;off>=1;off>>=1){ s1+=__shfl_xor(s1,off,64); s2+=__shfl_xor(s2,off,64); }
  if(lane==0){ red[0][wv]=s1; red[1][wv]=s2; }
  __syncthreads();
  if(t==0){
    float a=0.f,b=0.f;
    #pragma unroll
    for(int i=0;i<16;i++){ a+=red[0][i]; b+=red[1][i]; }
    stats[blk*2+0]=a; stats[blk*2+1]=b;
  }
}

// ---------------- K4: per-batch global norm + exact GELU, in place on d_out ----------------
__global__ __launch_bounds__(256) void k_final(float* __restrict__ out,
    const float* __restrict__ stats, const float* __restrict__ gg,
    const float* __restrict__ gb){
  __shared__ float red[64][2];
  __shared__ float mv[2];
  int blk = blockIdx.x; int bb = blk>>6, h = blk&63;
  int t = threadIdx.x;
  if(t<64){ red[t][0] = stats[(bb*64+t)*2+0]; red[t][1] = stats[(bb*64+t)*2+1]; }
  __syncthreads();
  if(t==0){
    float s1=0.f,s2=0.f;
    for(int i=0;i<64;i++){ s1+=red[i][0]; s2+=red[i][1]; }
    float mu = s1*(1.f/1048576.f);
    float var = s2*(1.f/1048576.f) - mu*mu;
    mv[0]=mu; mv[1]=rsqrtf(var+EPSF);
  }
  __syncthreads();
  float mu = mv[0], rs = mv[1];
  for(int i=0;i<64;i++){ int idx=t+256*i; int o=idx>>6, w=idx&63;
    size_t gidx = (size_t)((bb*256+o)*64+h)*64+w;
    float v = out[gidx];
    float yn = (v-mu)*rs*gg[o] + gb[o];
    out[gidx] = 0.5f*yn*(1.f+erff(yn*0.70710678118654752f));
  }
}

extern "C" void kernel_launch(void* const* d_in, const int* in_sizes, int n_in,
                              void* d_out, int out_size, void* d_ws, size_t ws_size,
                              hipStream_t stream) {
  const float* x     = (const float*)d_in[0];
  const float* Q1    = (const float*)d_in[1];
  // d_in[2] = Q2 : unused by the reference
  const float* Sx    = (const float*)d_in[3];
  const float* lng   = (const float*)d_in[4];
  const float* lnb   = (const float*)d_in[5];
  const float* Wi    = (const float*)d_in[6];
  const float* convw = (const float*)d_in[7];
  const float* convb = (const float*)d_in[8];
  const float* dtb   = (const float*)d_in[9];
  const float* alog  = (const float*)d_in[10];
  const float* dskip = (const float*)d_in[11];
  const float* normw = (const float*)d_in[12];
  const float* Wo    = (const float*)d_in[13];
  const float* gg    = (const float*)d_in[14];
  const float* gb    = (const float*)d_in[15];
  const float* W1    = (const float*)d_in[16];
  float* out = (float*)d_out;
  char* ws = (char*)d_ws;

  // ws layout (~94 MiB; ws_size = 256 MiB)
  size_t o = 0;
  u16*   xnb  = (u16*)(ws + o);  o += (size_t)16384*256*2;        // 8 MB  xn bf16
  u16*   zgb  = (u16*)(ws + o);  o += (size_t)16384*512*2;        // 16 MB
  u16*   xbc  = (u16*)(ws + o);  o += (size_t)16384*640*2;        // 20 MB raw xBC
  u16*   bH0  = (u16*)(ws + o);  o += (size_t)16384*128*2;        // 4 MB conv'd B/C
  u16*   bH1  = (u16*)(ws + o);  o += (size_t)16384*128*2;        // 4 MB
  u16*   bV0  = (u16*)(ws + o);  o += (size_t)16384*128*2;        // 4 MB
  u16*   bV1  = (u16*)(ws + o);  o += (size_t)16384*128*2;        // 4 MB
  u16*   UHs  = (u16*)(ws + o);  o += (size_t)16384*512*2;        // 16 MB (summed dirs)
  u16*   UVs  = (u16*)(ws + o);  o += (size_t)16384*512*2;        // 16 MB
  float* dtp  = (float*)(ws + o); o += (size_t)131072*4;          // 0.5 MB
  float* dtA  = (float*)(ws + o); o += (size_t)131072*4;          // 0.5 MB
  float* stats= (float*)(ws + o); o += 4096;
  u16*   WiF  = (u16*)(ws + o);  o += (size_t)73*8*64*8*2;        // 584 KB
  u16*   WCF  = (u16*)(ws + o);  o += (size_t)16384*8*2;          // 256 KB

  k_ln<<<256, 256, 0, stream>>>(x, lng, lnb, xnb);
  k_prep<<<658, 256, 0, stream>>>(Wi, WiF, Wo, W1, WCF);
  k_gemm_in<<<1280, 512, 0, stream>>>(xnb, WiF, dtb, alog,
                                      zgb, xbc, dtp, dtA);
  k_convBC<<<dim3(256,4), 512, 0, stream>>>(xbc, convw, convb, bH0, bH1, bV0, bV1);
  k_scan2<<<512, 512, 0, stream>>>(xbc, bH0, bH1, bV0, bV1, zgb, convw, convb,
                                   dtp, dtA, dskip, normw, UHs, UVs);
  k_blendfinal<<<256, 1024, 0, stream>>>(UHs, UVs, Q1, Sx, WCF, out, stats);
  k_final<<<256, 256, 0, stream>>>(out, stats, gg, gb);
}

// Round 21
// 168.595 us; speedup vs baseline: 1.2387x; 1.2383x over previous
//
#include <hip/hip_runtime.h>
#include <hip/hip_bf16.h>

// Problem constants (B,DIM,H,W)=(4,256,64,64), DSTATE=64, EXPAND=2, DCONV=4
// DINNER=512, HEADDIM=64, NHEADS=8, DINPROJ=1160, CONVDIM=640, EPS=1e-5
#define EPSF 1e-5f

typedef unsigned short u16;
typedef __attribute__((ext_vector_type(8))) short short8;   // 8 x bf16 MFMA operand
typedef __attribute__((ext_vector_type(4))) float f32x4;    // MFMA accumulator

__device__ __forceinline__ float sigf(float x){ return 1.f/(1.f+__expf(-x)); }
__device__ __forceinline__ float siluf(float x){ return x/(1.f+__expf(-x)); }
__device__ __forceinline__ u16 f2bf(float x){ __hip_bfloat16 h = __float2bfloat16(x); return *reinterpret_cast<u16*>(&h); }
__device__ __forceinline__ float bf2f(u16 u){ __hip_bfloat16 h; *reinterpret_cast<u16*>(&h) = u; return __bfloat162float(h); }

union BF8 { short8 v; u16 h[8]; uint4 q; };

__device__ __forceinline__ short8 ldg_frag(const u16* p){
  BF8 u; u.q = *(const uint4*)p; return u.v;
}
#define MFMA16(a,b,c) __builtin_amdgcn_mfma_f32_16x16x32_bf16((a),(b),(c),0,0,0)

// ---------------- K0: channel LayerNorm, x (B,C,H,W) -> xn bf16 (B,H,W,C) ----------------
__global__ __launch_bounds__(256) void k_ln(const float* __restrict__ x,
                                            const float* __restrict__ g,
                                            const float* __restrict__ b,
                                            u16* __restrict__ xn){
  __shared__ float XL[256][65];
  __shared__ float red[2][4][64];
  __shared__ float muL[64], rsL[64];
  int blk = blockIdx.x; int bb = blk>>6, h = blk&63;
  int t = threadIdx.x;
  const float* xb = x + ((size_t)bb*256*4096) + h*64;
  for(int i=0;i<64;i++){ int idx = t + 256*i; int c = idx>>6, w = idx&63;
    XL[c][w] = xb[(size_t)c*4096 + w]; }
  __syncthreads();
  { int w = t & 63, q = t >> 6;
    float s1=0, s2=0;
    for(int c=q*64;c<q*64+64;c++){ float v = XL[c][w]; s1+=v; s2+=v*v; }
    red[0][q][w]=s1; red[1][q][w]=s2; }
  __syncthreads();
  if(t<64){ float a=0,c2=0;
    for(int q=0;q<4;q++){a+=red[0][q][t]; c2+=red[1][q][t];}
    float mu=a*(1.f/256.f); float var=c2*(1.f/256.f)-mu*mu;
    muL[t]=mu; rsL[t]=rsqrtf(var+EPSF); }
  __syncthreads();
  u16* xnb = xn + (size_t)(bb*64+h)*64*256;
  for(int i=0;i<64;i++){ int idx = t + 256*i; int w = idx>>8, c = idx&255;
    float v = (XL[c][w]-muL[w])*rsL[w]*g[c]+b[c];
    xnb[w*256 + c] = f2bf(v); }
}

// ---------------- K_prep: pack Wi frags (blocks 0..145) + Wcomb=Wo@W1^T (blocks 146..657) ----
__global__ __launch_bounds__(256) void k_prep(const float* __restrict__ Wi,
                                              u16* __restrict__ WiF,
                                              const float* __restrict__ Wo,
                                              const float* __restrict__ W1,
                                              u16* __restrict__ WCF){
  __shared__ float WoL[256];
  int blk = blockIdx.x;
  int t = threadIdx.x;
  if(blk < 146){
    int f = blk*256 + t;                  // 37376 threads exactly
    int lane = f & 63, kk = (f>>6)&7, ji = f>>9;
    int g = lane>>4, c16 = lane&15;
    int j = ji*16 + c16;
    BF8 o;
    #pragma unroll
    for(int i=0;i<8;i++){
      int k = kk*32 + g*8 + i;
      o.h[i] = (j < 1160) ? f2bf(Wi[(size_t)k*1160 + j]) : (u16)0;
    }
    *(uint4*)(WiF + (size_t)f*8) = o.q;
  } else {
    int k = blk - 146;                    // 0..511
    int o = t;                            // 0..255
    WoL[o] = Wo[(size_t)k*256 + o];
    __syncthreads();
    const float4* w1p = (const float4*)(W1 + (size_t)o*256);
    const float4* wop = (const float4*)WoL;
    float d = 0.f;
    #pragma unroll 8
    for(int i=0;i<64;i++){
      float4 a = wop[i]; float4 b = w1p[i];
      d += a.x*b.x + a.y*b.y + a.z*b.z + a.w*b.w;
    }
    int kk = k>>5, g = (k>>3)&3, i2 = k&7;
    int ci = o>>4, c16 = o&15;
    WCF[(size_t)((((ci*16+kk)*4+g)*16+c16)*8 + i2)] = f2bf(d);
  }
}

// ---------------- K1: in-projection GEMM (once; direction-independent) ----------------
// grid 1280 1D, XCD-swizzled so the 5 col-chunk blocks of each row-block share one XCD L2.
__global__ __launch_bounds__(512, 4) void k_gemm_in(const u16* __restrict__ xn,
    const u16* __restrict__ WiF, const float* __restrict__ dtb,
    const float* __restrict__ alog,
    u16* __restrict__ zg, u16* __restrict__ xbc,
    float* __restrict__ dtp, float* __restrict__ dtA){
  __shared__ u16 XL[64][264];     // A tile 64x256 bf16, pad 264 (33.8 KB)
  int id = blockIdx.x;
  int xcd = id & 7;
  int rem = id >> 3;              // 0..159
  int rb_local = rem / 5;
  int cb = rem - rb_local*5;
  int rb = xcd*32 + rb_local;
  int t = threadIdx.x;
  int w = t>>6, lane = t&63, g = lane>>4, c16 = lane&15;

  const u16* asrc = xn + (size_t)rb*64*256;
  #pragma unroll
  for(int i=0;i<4;i++){
    int idx = t + 512*i;
    int row = idx>>5, ch = idx&31;
    *(uint4*)&XL[row][ch*8] = *(const uint4*)(asrc + (size_t)row*256 + ch*8);
  }
  __syncthreads();

  int jbase = cb*15;
  int jcount = (cb==4) ? 13 : 15;
  int jl0 = w*2;

  f32x4 acc[2][4];
  #pragma unroll
  for(int jj=0;jj<2;jj++){
    #pragma unroll
    for(int li=0;li<4;li++) acc[jj][li] = (f32x4){0.f,0.f,0.f,0.f};
  }
  #pragma unroll
  for(int kk=0;kk<8;++kk){
    short8 a0 = *(const short8*)&XL[ 0 + c16][kk*32+g*8];
    short8 a1 = *(const short8*)&XL[16 + c16][kk*32+g*8];
    short8 a2 = *(const short8*)&XL[32 + c16][kk*32+g*8];
    short8 a3 = *(const short8*)&XL[48 + c16][kk*32+g*8];
    #pragma unroll
    for(int jj=0;jj<2;++jj){
      if(jl0+jj < jcount){
        int ji = jbase + jl0 + jj;
        short8 bf = ldg_frag(WiF + ((size_t)(ji*8+kk)*64 + lane)*8);
        acc[jj][0] = MFMA16(a0, bf, acc[jj][0]);
        acc[jj][1] = MFMA16(a1, bf, acc[jj][1]);
        acc[jj][2] = MFMA16(a2, bf, acc[jj][2]);
        acc[jj][3] = MFMA16(a3, bf, acc[jj][3]);
      }
    }
  }
  int mbase = rb*64;
  #pragma unroll
  for(int jj=0;jj<2;++jj){
    if(jl0+jj >= jcount) continue;
    int ji = jbase + jl0 + jj;
    if(ji < 32){                           // z -> silu -> zg
      int col = ji*16 + c16;
      #pragma unroll
      for(int li=0;li<4;li++){
        #pragma unroll
        for(int r2=0;r2<4;r2++)
          zg[(size_t)(mbase + li*16 + g*4 + r2)*512 + col] = f2bf(siluf(acc[jj][li][r2]));
      }
    } else if(ji < 72){                    // xBC raw (pre-conv), bf16
      int col = ji*16 + c16 - 512;
      #pragma unroll
      for(int li=0;li<4;li++){
        #pragma unroll
        for(int r2=0;r2<4;r2++)
          xbc[(size_t)(mbase + li*16 + g*4 + r2)*640 + col] = f2bf(acc[jj][li][r2]);
      }
    } else if(c16 < 8){                    // dt (cols 1152..1159)
      int hd = c16;
      float A = -expf(alog[hd]);
      float bias = dtb[hd];
      #pragma unroll
      for(int li=0;li<4;li++){
        #pragma unroll
        for(int r2=0;r2<4;r2++){
          int m = mbase + li*16 + g*4 + r2;
          float v = acc[jj][li][r2] + bias;
          float sp = (v>20.f)? v : log1pf(expf(v));
          dtp[(size_t)((m>>6)*8 + hd)*64 + (m&63)] = sp;
          dtA[(size_t)((m>>6)*8 + hd)*64 + (m&63)] = sp*A;
        }
      }
    }
  }
}

// ---------------- K1d: conv of B/C channels ONLY (orig cols 512..639), 4 senses ----------
// grid 1024 1D XCD-swizzled: xcd=id&7, rem=id>>3, s=xcd*32+(rem>>2), y=rem&3 — the 4
// senses of each seq share one XCD L2 (B/C columns read 4x).
// block 512: thread -> (scan row u = t>>3, col-group cg = t&7).
// Output compact [seq][64][128] bf16 (B at 0..63, C at 64..127).
__global__ __launch_bounds__(512) void k_convBC(const u16* __restrict__ xbc,
    const float* __restrict__ convw, const float* __restrict__ convb,
    u16* __restrict__ bH0, u16* __restrict__ bH1,
    u16* __restrict__ bV0, u16* __restrict__ bV1){
  int id = blockIdx.x;
  int xcd = id & 7;
  int rem = id >> 3;                 // 0..127
  int s = xcd*32 + (rem>>2);
  int y = rem & 3;
  int dirb = y&1, dirV = y>>1;
  int t = threadIdx.x;
  int u = t>>3, cg = t&7;
  int b_ = s>>6, r_ = s&63;
  int cB = 512 + cg*8, cC = 576 + cg*8;
  float4 cwB[8], cwC[8]; float cbB[8], cbC[8];
  #pragma unroll
  for(int i=0;i<8;i++){
    cwB[i] = *(const float4*)(convw + (size_t)(cB+i)*4);
    cwC[i] = *(const float4*)(convw + (size_t)(cC+i)*4);
    cbB[i] = convb[cB+i]; cbC[i] = convb[cC+i];
  }
  BF8 wB[4], wC[4];
  #pragma unroll
  for(int j=0;j<4;j++){
    int p = u - 3 + j;                       // scan-coord window
    if(p >= 0){
      int m = dirb ? 63-p : p;
      size_t row = dirV ? ((size_t)b_*4096 + (size_t)m*64 + r_) : ((size_t)s*64 + m);
      wB[j].q = *(const uint4*)(xbc + row*640 + cB);
      wC[j].q = *(const uint4*)(xbc + row*640 + cC);
    } else { wB[j].q = (uint4){0u,0u,0u,0u}; wC[j].q = (uint4){0u,0u,0u,0u}; }
  }
  BF8 oB, oC;
  #pragma unroll
  for(int ch=0; ch<8; ++ch){
    float vB = cbB[ch] + cwB[ch].w*bf2f(wB[3].h[ch]) + cwB[ch].z*bf2f(wB[2].h[ch])
                       + cwB[ch].y*bf2f(wB[1].h[ch]) + cwB[ch].x*bf2f(wB[0].h[ch]);
    float vC = cbC[ch] + cwC[ch].w*bf2f(wC[3].h[ch]) + cwC[ch].z*bf2f(wC[2].h[ch])
                       + cwC[ch].y*bf2f(wC[1].h[ch]) + cwC[ch].x*bf2f(wC[0].h[ch]);
    oB.h[ch] = f2bf(siluf(vB));
    oC.h[ch] = f2bf(siluf(vC));
  }
  u16* dst = ((y==0)? bH0 : (y==1)? bH1 : (y==2)? bV0 : bV1) + ((size_t)(s*64+u))*128;
  *(uint4*)(dst + cg*8)      = oB.q;
  *(uint4*)(dst + 64 + cg*8) = oC.q;
}

// ---------------- K2: SSD scan with in-LDS X-conv, all 4 variants, one launch ----------
// grid 1024 1D, XCD-swizzled: xcd=id&7, rem=id>>3, s=xcd*32+(rem>>2), y=rem&3 — the 4
// variants of each seq share one XCD L2 (X slab read 4x). 512 thr = 8 waves (head/wave).
// Stages RAW X (scan order) into XV, convs in LDS (strided rows, r16 pattern),
// B/C from k_convBC buffers. Emits RAW Y (bf16, orig-l order).
__global__ __launch_bounds__(512, 4) void k_scan4(
    const u16* __restrict__ xbc,
    const u16* __restrict__ bH0, const u16* __restrict__ bH1,
    const u16* __restrict__ bV0, const u16* __restrict__ bV1,
    const float* __restrict__ convw, const float* __restrict__ convb,
    const float* __restrict__ dtp_g, const float* __restrict__ dtA_g,
    const float* __restrict__ dskip,
    u16* __restrict__ UH0, u16* __restrict__ UH1,
    u16* __restrict__ UV0, u16* __restrict__ UV1){
  // XV [64][520] bf16 66560 | Gtri 2080 f32 8320 | sL 2048 | dtL 2048 = 78976 B
  __shared__ __align__(16) char smem[78976];
  u16 (*XV)[520] = (u16(*)[520])smem;
  float* Gtri = (float*)(smem + 66560);
  float* sL   = (float*)(smem + 74880);
  float* dtL  = (float*)(smem + 76928);

  int id = blockIdx.x;
  int xcd = id & 7;
  int rem = id >> 3;                 // 0..127
  int s = xcd*32 + (rem>>2);
  int y = rem & 3;
  int t = threadIdx.x;
  int dirb = y&1, dirV = y>>1;
  int w = t>>6, lane = t&63, g = lane>>4, c16 = lane&15;
  int b_ = s>>6, r_ = s&63;
  float dsk = dskip[w];
  const u16* xc = ((y==0)? bH0 : (y==1)? bH1 : (y==2)? bV0 : bV1) + (size_t)s*64*128;
  u16* un = ((y==0)? UH0 : (y==1)? UH1 : (y==2)? UV0 : UV1) + (size_t)s*64*512;

  // ---- per-head prefix sum of dt*A in scan coords (wave-local) ----
  {
    int tt = dirb ? 63-lane : lane;
    size_t dti = dirV ? ((size_t)((b_*64 + tt)*8 + w))*64 + r_
                      : ((size_t)(s*8 + w))*64 + tt;
    float a = dtA_g[dti];
    float d = dtp_g[dti];
    #pragma unroll
    for(int off=1; off<64; off<<=1){
      float nb = __shfl_up(a, off, 64);
      if(lane >= off) a += nb;
    }
    sL[w*64+lane] = a;
    dtL[w*64+lane] = d;
  }
  // ---- G = C @ B^T from conv'd compact B/C; wave w -> tiles 2w, 2w+1; lower-tri only ----
  #pragma unroll
  for(int tt2=0; tt2<2; ++tt2){
    int tile = 2*w + tt2, li = tile>>2, ji = tile&3;
    f32x4 acc = {0.f,0.f,0.f,0.f};
    #pragma unroll
    for(int kk=0; kk<2; ++kk){
      short8 af = ldg_frag(xc + (size_t)(li*16 + c16)*128 + 64 + kk*32 + g*8); // C rows
      short8 bf = ldg_frag(xc + (size_t)(ji*16 + c16)*128 +      kk*32 + g*8); // B rows
      acc = MFMA16(af, bf, acc);
    }
    int col = ji*16 + c16;
    #pragma unroll
    for(int r=0;r<4;r++){
      int row = li*16 + g*4 + r;
      if(col <= row) Gtri[(row*(row+1))/2 + col] = acc[r];
    }
  }
  // ---- stage RAW X (cols 0..511, scan order) into XV ----
  int c0 = lane*8;
  #pragma unroll
  for(int it=0; it<8; ++it){
    int tr = w + 8*it;
    int m = dirb ? 63-tr : tr;
    size_t row = dirV ? ((size_t)b_*4096 + (size_t)m*64 + r_) : ((size_t)s*64 + m);
    *(uint4*)&XV[tr][c0] = *(const uint4*)(xbc + row*640 + c0);
  }
  __syncthreads();
  // ---- conv X in LDS (scan-coord FIR, sense-independent), two-phase, strided rows ----
  {
    float4 cwx[8]; float cbx[8];
    #pragma unroll
    for(int i=0;i<8;i++){
      cwx[i] = *(const float4*)(convw + (size_t)(c0+i)*4);
      cbx[i] = convb[c0+i];
    }
    BF8 outr[8];
    #pragma unroll
    for(int it=0; it<8; ++it){
      int tr = w + 8*it;
      BF8 wnd[4];
      #pragma unroll
      for(int j=0;j<4;j++){
        int p = tr - 3 + j;
        if(p >= 0) wnd[j].q = *(const uint4*)&XV[p][c0];
        else       wnd[j].q = (uint4){0u,0u,0u,0u};
      }
      #pragma unroll
      for(int ch=0; ch<8; ++ch){
        float v = cbx[ch] + cwx[ch].w*bf2f(wnd[3].h[ch]) + cwx[ch].z*bf2f(wnd[2].h[ch])
                          + cwx[ch].y*bf2f(wnd[1].h[ch]) + cwx[ch].x*bf2f(wnd[0].h[ch]);
        outr[it].h[ch] = f2bf(siluf(v));
      }
    }
    __syncthreads();
    #pragma unroll
    for(int it=0; it<8; ++it)
      *(uint4*)&XV[w + 8*it][c0] = outr[it].q;
  }
  __syncthreads();
  // ---- X-frags preload (own head's 64 cols; frees XV rows for Y writes) ----
  short8 xfr[4][2];
  #pragma unroll
  for(int pi=0; pi<4; ++pi){
    #pragma unroll
    for(int kk=0; kk<2; ++kk){
      BF8 u;
      #pragma unroll
      for(int i=0;i<8;i++){
        int uu = kk*32 + g*8 + i;
        u.h[i] = XV[uu][w*64 + pi*16 + c16];
      }
      xfr[pi][kk] = u.v;
    }
  }
  // ---- per l-tile: build M fragments, Y = M@X, write raw Y (orig-l order) ----
  #pragma unroll 1
  for(int li=0; li<4; ++li){
    int tr = li*16 + c16;            // A-frag row (scan coord)
    float sl = sL[w*64 + tr];
    int tb = (tr*(tr+1))/2;
    short8 mfr[2];
    #pragma unroll
    for(int kk=0; kk<2; ++kk){
      BF8 u;
      #pragma unroll
      for(int i=0;i<8;i++){
        int uu = kk*32 + g*8 + i;
        float m = 0.f;
        if(uu <= tr){
          m = __expf(sl - sL[w*64+uu]) * dtL[w*64+uu] * Gtri[tb + uu];
          if(uu == tr) m += dsk;     // Dskip folded into diagonal (exact)
        }
        u.h[i] = f2bf(m);
      }
      mfr[kk] = u.v;
    }
    #pragma unroll
    for(int pi=0; pi<4; ++pi){
      f32x4 acc = {0.f,0.f,0.f,0.f};
      acc = MFMA16(mfr[0], xfr[pi][0], acc);
      acc = MFMA16(mfr[1], xfr[pi][1], acc);
      #pragma unroll
      for(int r=0;r<4;r++){
        int trow = li*16 + g*4 + r;
        int lorig = dirb ? 63-trow : trow;
        XV[lorig][w*64 + pi*16 + c16] = f2bf(acc[r]);
      }
    }
  }
  __syncthreads();
  // ---- dump raw Y rows to global (coalesced) ----
  #pragma unroll
  for(int rr=0; rr<8; ++rr){
    int l = w*8 + rr;
    *(uint4*)(un + (size_t)l*512 + lane*8) = *(const uint4*)&XV[l][lane*8];
  }
}

// ---------------- K3: gate+RMSNorm (4 variants) + blend + Wcomb GEMM + stats ----------------
// grid 256 = (bb,h); block 1024 = 16 waves; wave wv loads rows wv+16i and owns o-tile wv.
__global__ __launch_bounds__(1024, 4) void k_blendfinal(
    const u16* __restrict__ UH0, const u16* __restrict__ UH1,
    const u16* __restrict__ UV0, const u16* __restrict__ UV1,
    const u16* __restrict__ zg, const float* __restrict__ normw,
    const float* __restrict__ Q1, const float* __restrict__ Sx,
    const u16* __restrict__ WCF,
    float* __restrict__ out, float* __restrict__ stats){
  __shared__ u16 A[64][520];
  __shared__ float asL[64], bsL[64];
  __shared__ float nwL[512];
  __shared__ float red[2][16];
  int blk = blockIdx.x; int bb = blk>>6, h = blk&63;
  int t = threadIdx.x;
  if(t<64){
    float qv = Q1[bb*4096 + h*64 + t];
    float sv = Sx[bb*4096 + h*64 + t];
    float al = sigf(qv);
    float sc = 0.5f + 0.5f*sv;
    asL[t] = al*sc; bsL[t] = (1.f-al)*sc;
  }
  if(t < 512) nwL[t] = normw[t];
  __syncthreads();
  int wv = t>>6, lane = t&63, g = lane>>4, c16 = lane&15;
  #pragma unroll 1
  for(int i=0;i<4;i++){
    int wp = wv + 16*i;
    int c8 = lane*8;
    size_t rH = ((size_t)((bb*64+h)*64 + wp))*512 + c8;
    size_t rV = ((size_t)((bb*64+wp)*64 + h))*512 + c8;
    BF8 h0,h1,v0,v1,z8;
    h0.q = *(const uint4*)(UH0 + rH);
    h1.q = *(const uint4*)(UH1 + rH);
    v0.q = *(const uint4*)(UV0 + rV);
    v1.q = *(const uint4*)(UV1 + rV);
    z8.q = *(const uint4*)(zg  + rH);
    float gh0[8], gh1[8], gv0[8], gv1[8];
    float sh0=0.f, sh1=0.f, sv0=0.f, sv1=0.f;
    #pragma unroll
    for(int j=0;j<8;j++){
      float zv = bf2f(z8.h[j]);
      gh0[j] = bf2f(h0.h[j])*zv; sh0 += gh0[j]*gh0[j];
      gh1[j] = bf2f(h1.h[j])*zv; sh1 += gh1[j]*gh1[j];
      gv0[j] = bf2f(v0.h[j])*zv; sv0 += gv0[j]*gv0[j];
      gv1[j] = bf2f(v1.h[j])*zv; sv1 += gv1[j]*gv1[j];
    }
    #pragma unroll
    for(int off=32; off>=1; off>>=1){
      sh0 += __shfl_xor(sh0, off, 64); sh1 += __shfl_xor(sh1, off, 64);
      sv0 += __shfl_xor(sv0, off, 64); sv1 += __shfl_xor(sv1, off, 64);
    }
    float rh0 = rsqrtf(sh0*(1.f/512.f)+EPSF);
    float rh1 = rsqrtf(sh1*(1.f/512.f)+EPSF);
    float rv0 = rsqrtf(sv0*(1.f/512.f)+EPSF);
    float rv1 = rsqrtf(sv1*(1.f/512.f)+EPSF);
    float aw = 0.5f*asL[wp], bw = 0.5f*bsL[wp];
    BF8 o;
    #pragma unroll
    for(int j=0;j<8;j++){
      float u = nwL[c8+j]*(aw*(gh0[j]*rh0 + gh1[j]*rh1) + bw*(gv0[j]*rv0 + gv1[j]*rv1));
      o.h[j] = f2bf(u);
    }
    *(uint4*)&A[wp][c8] = o.q;
  }
  __syncthreads();
  int ci = wv;
  f32x4 acc0={0.f,0.f,0.f,0.f}, acc1=acc0, acc2=acc0, acc3=acc0;
  #pragma unroll 2
  for(int kk=0; kk<16; ++kk){
    short8 bfr = ldg_frag(WCF + (size_t)((((ci*16+kk)*4+g)*16+c16)*8));
    short8 a0 = *(const short8*)&A[ 0+c16][kk*32+g*8];
    short8 a1 = *(const short8*)&A[16+c16][kk*32+g*8];
    short8 a2 = *(const short8*)&A[32+c16][kk*32+g*8];
    short8 a3 = *(const short8*)&A[48+c16][kk*32+g*8];
    acc0 = MFMA16(a0,bfr,acc0); acc1 = MFMA16(a1,bfr,acc1);
    acc2 = MFMA16(a2,bfr,acc2); acc3 = MFMA16(a3,bfr,acc3);
  }
  float s1=0.f, s2=0.f;
  int o_ = ci*16 + c16;
  #pragma unroll
  for(int li=0; li<4; ++li){
    f32x4 a = (li==0)?acc0 : (li==1)?acc1 : (li==2)?acc2 : acc3;
    int w0 = li*16 + g*4;
    float4 vv = {a[0], a[1], a[2], a[3]};
    s1 += (vv.x+vv.y)+(vv.z+vv.w);
    s2 += (vv.x*vv.x+vv.y*vv.y)+(vv.z*vv.z+vv.w*vv.w);
    *(float4*)(out + (((size_t)(bb*256+o_)*64 + h)*64 + w0)) = vv;
  }
  #pragma unroll
  for(int off=32;off>=1;off>>=1){ s1+=__shfl_xor(s1,off,64); s2+=__shfl_xor(s2,off,64); }
  if(lane==0){ red[0][wv]=s1; red[1][wv]=s2; }
  __syncthreads();
  if(t==0){
    float a=0.f,b=0.f;
    #pragma unroll
    for(int i=0;i<16;i++){ a+=red[0][i]; b+=red[1][i]; }
    stats[blk*2+0]=a; stats[blk*2+1]=b;
  }
}

// ---------------- K4: per-batch global norm + exact GELU, in place on d_out ----------------
__global__ __launch_bounds__(256) void k_final(float* __restrict__ out,
    const float* __restrict__ stats, const float* __restrict__ gg,
    const float* __restrict__ gb){
  __shared__ float red[64][2];
  __shared__ float mv[2];
  int blk = blockIdx.x; int bb = blk>>6, h = blk&63;
  int t = threadIdx.x;
  if(t<64){ red[t][0] = stats[(bb*64+t)*2+0]; red[t][1] = stats[(bb*64+t)*2+1]; }
  __syncthreads();
  if(t==0){
    float s1=0.f,s2=0.f;
    for(int i=0;i<64;i++){ s1+=red[i][0]; s2+=red[i][1]; }
    float mu = s1*(1.f/1048576.f);
    float var = s2*(1.f/1048576.f) - mu*mu;
    mv[0]=mu; mv[1]=rsqrtf(var+EPSF);
  }
  __syncthreads();
  float mu = mv[0], rs = mv[1];
  for(int i=0;i<64;i++){ int idx=t+256*i; int o=idx>>6, w=idx&63;
    size_t gidx = (size_t)((bb*256+o)*64+h)*64+w;
    float v = out[gidx];
    float yn = (v-mu)*rs*gg[o] + gb[o];
    out[gidx] = 0.5f*yn*(1.f+erff(yn*0.70710678118654752f));
  }
}

extern "C" void kernel_launch(void* const* d_in, const int* in_sizes, int n_in,
                              void* d_out, int out_size, void* d_ws, size_t ws_size,
                              hipStream_t stream) {
  const float* x     = (const float*)d_in[0];
  const float* Q1    = (const float*)d_in[1];
  // d_in[2] = Q2 : unused by the reference
  const float* Sx    = (const float*)d_in[3];
  const float* lng   = (const float*)d_in[4];
  const float* lnb   = (const float*)d_in[5];
  const float* Wi    = (const float*)d_in[6];
  const float* convw = (const float*)d_in[7];
  const float* convb = (const float*)d_in[8];
  const float* dtb   = (const float*)d_in[9];
  const float* alog  = (const float*)d_in[10];
  const float* dskip = (const float*)d_in[11];
  const float* normw = (const float*)d_in[12];
  const float* Wo    = (const float*)d_in[13];
  const float* gg    = (const float*)d_in[14];
  const float* gb    = (const float*)d_in[15];
  const float* W1    = (const float*)d_in[16];
  float* out = (float*)d_out;
  char* ws = (char*)d_ws;

  // ws layout (~126 MiB; ws_size = 256 MiB)
  size_t o = 0;
  u16*   xnb  = (u16*)(ws + o);  o += (size_t)16384*256*2;        // 8 MB  xn bf16
  u16*   zgb  = (u16*)(ws + o);  o += (size_t)16384*512*2;        // 16 MB
  u16*   xbc  = (u16*)(ws + o);  o += (size_t)16384*640*2;        // 20 MB raw xBC
  u16*   bH0  = (u16*)(ws + o);  o += (size_t)16384*128*2;        // 4 MB conv'd B/C
  u16*   bH1  = (u16*)(ws + o);  o += (size_t)16384*128*2;        // 4 MB
  u16*   bV0  = (u16*)(ws + o);  o += (size_t)16384*128*2;        // 4 MB
  u16*   bV1  = (u16*)(ws + o);  o += (size_t)16384*128*2;        // 4 MB
  u16*   UH0  = (u16*)(ws + o);  o += (size_t)16384*512*2;        // 16 MB
  u16*   UH1  = (u16*)(ws + o);  o += (size_t)16384*512*2;        // 16 MB
  u16*   UV0  = (u16*)(ws + o);  o += (size_t)16384*512*2;        // 16 MB
  u16*   UV1  = (u16*)(ws + o);  o += (size_t)16384*512*2;        // 16 MB
  float* dtp  = (float*)(ws + o); o += (size_t)131072*4;          // 0.5 MB
  float* dtA  = (float*)(ws + o); o += (size_t)131072*4;          // 0.5 MB
  float* stats= (float*)(ws + o); o += 4096;
  u16*   WiF  = (u16*)(ws + o);  o += (size_t)73*8*64*8*2;        // 584 KB
  u16*   WCF  = (u16*)(ws + o);  o += (size_t)16384*8*2;          // 256 KB

  k_ln<<<256, 256, 0, stream>>>(x, lng, lnb, xnb);
  k_prep<<<658, 256, 0, stream>>>(Wi, WiF, Wo, W1, WCF);
  k_gemm_in<<<1280, 512, 0, stream>>>(xnb, WiF, dtb, alog,
                                      zgb, xbc, dtp, dtA);
  k_convBC<<<1024, 512, 0, stream>>>(xbc, convw, convb, bH0, bH1, bV0, bV1);
  k_scan4<<<1024, 512, 0, stream>>>(xbc, bH0, bH1, bV0, bV1, convw, convb,
                                    dtp, dtA, dskip, UH0, UH1, UV0, UV1);
  k_blendfinal<<<256, 1024, 0, stream>>>(UH0, UH1, UV0, UV1, zgb, normw,
                                         Q1, Sx, WCF, out, stats);
  k_final<<<256, 256, 0, stream>>>(out, stats, gg, gb);
}